// Round 7
// baseline (65.830 us; speedup 1.0000x reference)
//
#include <hip/hip_runtime.h>
#include <hip/hip_bf16.h>
#include <stdint.h>

#define BB 32
#define NN 1024
#define MM 1024
#define DD 256

typedef __attribute__((ext_vector_type(8))) short short8;
typedef __attribute__((ext_vector_type(4))) float floatx4;

__device__ inline unsigned short f2bf(float x) {
    union { __hip_bfloat16 h; unsigned short u; } cv;
    cv.h = __float2bfloat16(x);
    return cv.u;
}

// async global->LDS, 16B/lane. LDS dest = wave-uniform base + lane*16.
__device__ inline void async_copy16(void* lds, const void* g) {
    __builtin_amdgcn_global_load_lds(
        (const __attribute__((address_space(1))) unsigned int*)g,
        (__attribute__((address_space(3))) unsigned int*)lds, 16, 0, 0);
}

// ---------------------------------------------------------------------------
__global__ __launch_bounds__(256) void init_minbuf(unsigned int* __restrict__ p) {
    p[blockIdx.x * 256 + threadIdx.x] = 0x7F800000u; // +inf
}

// ---------------------------------------------------------------------------
// Convert fp32 -> bf16 + per-row sum of squares (fp32 exact). One wave/row.
// ---------------------------------------------------------------------------
__global__ __launch_bounds__(256) void convert_kernel(
        const float* __restrict__ h1, const float* __restrict__ h2,
        __hip_bfloat16* __restrict__ h1b, __hip_bfloat16* __restrict__ h2b,
        float* __restrict__ sq1, float* __restrict__ sq2) {
    int wave = blockIdx.x * 4 + (threadIdx.x >> 6);
    int lane = threadIdx.x & 63;
    const int total1 = BB * NN;

    const float* src;
    __hip_bfloat16* dst;
    float* sq;
    int row;
    if (wave < total1) { src = h1; dst = h1b; sq = sq1; row = wave; }
    else               { src = h2; dst = h2b; sq = sq2; row = wave - total1; }

    const float4* p = (const float4*)(src + (size_t)row * DD);
    float4 v = p[lane];

    float s = v.x * v.x + v.y * v.y + v.z * v.z + v.w * v.w;
    #pragma unroll
    for (int off = 32; off; off >>= 1) s += __shfl_xor(s, off, 64);

    ushort4 o;
    o.x = f2bf(v.x); o.y = f2bf(v.y); o.z = f2bf(v.z); o.w = f2bf(v.w);
    *(ushort4*)((unsigned short*)(dst + (size_t)row * DD) + lane * 4) = o;

    if (lane == 0) sq[row] = s;
}

// ---------------------------------------------------------------------------
// 256x256-tile batched GEMM + fused Hausdorff epilogue.
// 512 threads = 8 waves (2 row-groups x 4 col-groups; wave tile 128n x 64m).
// BK=64 -> 4 K-steps; 2-buffer LDS (128 KB), global_load_lds w16 staging,
// both-sides XOR swizzle, RAW s_barrier + counted vmcnt (no __syncthreads
// full drain!). Grid (batch.x=32, tile.y=16): batch's 1 MB set L2-resident
// on XCD b%8. 512 blocks = exactly 2 per CU.
// ---------------------------------------------------------------------------
__global__ __launch_bounds__(512, 2) void gemm_kernel(
        const __hip_bfloat16* __restrict__ h1b, const __hip_bfloat16* __restrict__ h2b,
        const float* __restrict__ sq1, const float* __restrict__ sq2,
        unsigned int* __restrict__ rowmin, unsigned int* __restrict__ colmin) {
    __shared__ __align__(16) unsigned short As[2][256 * 64];   // 64 KB
    __shared__ __align__(16) unsigned short Bs[2][256 * 64];   // 64 KB

    const int b  = blockIdx.x;        // batch
    const int t  = blockIdx.y;        // 0..15
    const int n0 = (t >> 2) * 256;
    const int m0 = (t & 3) * 256;

    const int tid  = threadIdx.x;
    const int wave = tid >> 6;        // 0..7
    const int lane = tid & 63;
    const int wr   = (wave >> 2) * 128;   // wave row origin {0,128}
    const int wc   = (wave & 3) * 64;     // wave col origin {0,64,128,192}

    const char* Ag = (const char*)(h1b + ((size_t)b * NN + n0) * DD);
    const char* Bg = (const char*)(h2b + ((size_t)b * MM + m0) * DD);

    const int krow = lane >> 4;   // 0..3
    const int rrow = lane & 15;   // 0..15
    const int rx   = rrow & 7;

    // staging: 32 KB k-slice per matrix = 32 chunks of 1 KB (8 rows x 128 B).
    // LDS linear (HW: base + lane*16); global src unit inverse-XOR-swizzled.
    const int rl  = lane >> 3;            // row within chunk 0..7
    const int bcu = (lane & 7) ^ rl;      // swizzled source 16B unit

    #define STAGE(ks_, buf_)                                                  \
        {                                                                     \
            _Pragma("unroll")                                                 \
            for (int c = 0; c < 4; ++c) {                                     \
                int ch_ = wave * 4 + c;                                       \
                size_t go_ = (size_t)(ch_ * 8 + rl) * 512                     \
                           + (size_t)(ks_) * 128 + (bcu << 4);                \
                async_copy16((char*)&As[buf_][0] + ch_ * 1024, Ag + go_);     \
                async_copy16((char*)&Bs[buf_][0] + ch_ * 1024, Bg + go_);     \
            }                                                                 \
        }

    floatx4 acc[8][4] = {};

    STAGE(0, 0);
    STAGE(1, 1);

    #pragma unroll 1
    for (int ks = 0; ks < 4; ++ks) {
        const int buf = ks & 1;
        // stage(ks) complete; stage(ks+1)'s 8 copies may stay in flight
        if (ks < 3) { asm volatile("s_waitcnt vmcnt(8)" ::: "memory"); }
        else        { asm volatile("s_waitcnt vmcnt(0)" ::: "memory"); }
        __builtin_amdgcn_s_barrier();
        __builtin_amdgcn_sched_barrier(0);

        {
            const char* Ab = (const char*)&As[buf][0];
            const char* Bb = (const char*)&Bs[buf][0];
            #pragma unroll
            for (int kk = 0; kk < 2; ++kk) {
                const int u = ((kk << 2) | krow) ^ rx;   // swizzled 16B unit
                short8 af[8], bfv[4];
                #pragma unroll
                for (int i = 0; i < 8; ++i)
                    af[i] = *(const short8*)(Ab
                            + (size_t)(wr + i * 16 + rrow) * 128 + (u << 4));
                #pragma unroll
                for (int j = 0; j < 4; ++j)
                    bfv[j] = *(const short8*)(Bb
                             + (size_t)(wc + j * 16 + rrow) * 128 + (u << 4));
                #pragma unroll
                for (int i = 0; i < 8; ++i)
                    #pragma unroll
                    for (int j = 0; j < 4; ++j)
                        acc[i][j] = __builtin_amdgcn_mfma_f32_16x16x32_bf16(
                            af[i], bfv[j], acc[i][j], 0, 0, 0);
            }
        }

        __builtin_amdgcn_sched_barrier(0);
        asm volatile("s_waitcnt lgkmcnt(0)" ::: "memory");
        __builtin_amdgcn_s_barrier();
        // all waves done reading buf -> safe to overwrite with stage(ks+2)
        if (ks < 2) STAGE(ks + 2, buf);
    }

    // ---- epilogue (post-loop: no interaction with counted vmcnt) ----
    // D mapping (16x16x32 bf16): col = lane&15, row = (lane>>4)*4 + reg
    const float* s1 = sq1 + b * NN + n0 + wr;
    const float* s2 = sq2 + b * MM + m0 + wc;
    unsigned int* rm = rowmin + b * NN + n0 + wr;
    unsigned int* cm = colmin + b * MM + m0 + wc;

    const int lrow = krow * 4;
    const int lcol = rrow;

    float s2v[4];
    #pragma unroll
    for (int j = 0; j < 4; ++j) s2v[j] = s2[j * 16 + lcol];

    float cmin[4] = {3.0e38f, 3.0e38f, 3.0e38f, 3.0e38f};

    #pragma unroll
    for (int i = 0; i < 8; ++i) {
        const float4 s1q = *(const float4*)(s1 + i * 16 + lrow);
        #pragma unroll
        for (int r = 0; r < 4; ++r) {
            float s1x = ((const float*)&s1q)[r];
            float pm = 3.0e38f;
            #pragma unroll
            for (int j = 0; j < 4; ++j) {
                float dist = fmaxf(s1x + s2v[j] - 2.0f * acc[i][j][r], 0.0f);
                pm = fminf(pm, dist);
                cmin[j] = fminf(cmin[j], dist);
            }
            #pragma unroll
            for (int off = 1; off < 16; off <<= 1)
                pm = fminf(pm, __shfl_xor(pm, off, 64));
            if (lcol == 0)
                atomicMin(&rm[i * 16 + lrow + r], __float_as_uint(pm));
        }
    }

    #pragma unroll
    for (int j = 0; j < 4; ++j) {
        float c = cmin[j];
        c = fminf(c, __shfl_xor(c, 16, 64));
        c = fminf(c, __shfl_xor(c, 32, 64));
        if (krow == 0)
            atomicMin(&cm[j * 16 + lcol], __float_as_uint(c));
    }
    #undef STAGE
}

// ---------------------------------------------------------------------------
__global__ __launch_bounds__(256) void finalize_kernel(
        const unsigned int* __restrict__ rowmin,
        const unsigned int* __restrict__ colmin,
        float* __restrict__ out) {
    int b = blockIdx.x;
    int tid = threadIdx.x;
    float s = 0.0f;
    for (int i = tid; i < NN; i += 256) s += __uint_as_float(rowmin[b * NN + i]);
    for (int i = tid; i < MM; i += 256) s += __uint_as_float(colmin[b * MM + i]);
    #pragma unroll
    for (int off = 32; off; off >>= 1) s += __shfl_xor(s, off, 64);
    __shared__ float wsum[4];
    if ((tid & 63) == 0) wsum[tid >> 6] = s;
    __syncthreads();
    if (tid == 0) out[b] = (wsum[0] + wsum[1] + wsum[2] + wsum[3]) * (1.0f / 1024.0f);
}

// ---------------------------------------------------------------------------
extern "C" void kernel_launch(void* const* d_in, const int* in_sizes, int n_in,
                              void* d_out, int out_size, void* d_ws, size_t ws_size,
                              hipStream_t stream) {
    const float* h1 = (const float*)d_in[0];
    const float* h2 = (const float*)d_in[1];
    float* out = (float*)d_out;

    char* ws = (char*)d_ws;
    const size_t bf_bytes = (size_t)BB * NN * DD * sizeof(unsigned short); // 16 MB
    __hip_bfloat16* h1b = (__hip_bfloat16*)ws;
    __hip_bfloat16* h2b = (__hip_bfloat16*)(ws + bf_bytes);
    float* sq1 = (float*)(ws + 2 * bf_bytes);
    float* sq2 = sq1 + BB * NN;
    unsigned int* rowmin = (unsigned int*)(sq2 + BB * MM);
    unsigned int* colmin = rowmin + BB * NN;

    hipLaunchKernelGGL(init_minbuf, dim3(256), dim3(256), 0, stream, rowmin);

    hipLaunchKernelGGL(convert_kernel, dim3((BB * NN + BB * MM) / 4), dim3(256), 0, stream,
                       h1, h2, h1b, h2b, sq1, sq2);

    hipLaunchKernelGGL(gemm_kernel, dim3(BB, 16), dim3(512), 0, stream,
                       h1b, h2b, sq1, sq2, rowmin, colmin);

    hipLaunchKernelGGL(finalize_kernel, dim3(BB), dim3(256), 0, stream,
                       rowmin, colmin, out);
}

// Round 8
// 47.423 us; speedup vs baseline: 1.3882x; 1.3882x over previous
//
#include <hip/hip_runtime.h>
#include <hip/hip_bf16.h>
#include <stdint.h>

#define BB 32
#define NN 1024
#define MM 1024
#define DD 256

typedef __attribute__((ext_vector_type(8))) short short8;
typedef __attribute__((ext_vector_type(4))) float floatx4;

__device__ inline unsigned short f2bf(float x) {
    union { __hip_bfloat16 h; unsigned short u; } cv;
    cv.h = __float2bfloat16(x);
    return cv.u;
}

// async global->LDS. LDS dest = wave-uniform base; HW adds lane*size.
__device__ inline void async_copy16(void* lds, const void* g) {
    __builtin_amdgcn_global_load_lds(
        (const __attribute__((address_space(1))) unsigned int*)g,
        (__attribute__((address_space(3))) unsigned int*)lds, 16, 0, 0);
}
__device__ inline void async_copy4(void* lds, const void* g) {
    __builtin_amdgcn_global_load_lds(
        (const __attribute__((address_space(1))) unsigned int*)g,
        (__attribute__((address_space(3))) unsigned int*)lds, 4, 0, 0);
}

// ---------------------------------------------------------------------------
// Convert fp32 -> bf16 + per-row sum of squares + min-buffer init.
// One wave per TWO rows (32 B/lane). Grid 8192 x 256.
// ---------------------------------------------------------------------------
__global__ __launch_bounds__(256) void convert_kernel(
        const float* __restrict__ h1, const float* __restrict__ h2,
        unsigned short* __restrict__ h1b, unsigned short* __restrict__ h2b,
        float* __restrict__ sq1, float* __restrict__ sq2,
        unsigned int* __restrict__ minb) {
    // fold rowmin/colmin init (65536 uints) into first 256 blocks
    int g = blockIdx.x * 256 + threadIdx.x;
    if (g < 2 * BB * NN) minb[g] = 0x7F800000u;

    int wid  = blockIdx.x * 4 + (threadIdx.x >> 6);
    int lane = threadIdx.x & 63;
    int l5   = lane & 31;
    int row  = wid * 2 + (lane >> 5);
    const int total1 = BB * NN;

    const float* src; unsigned short* dst; float* sq; int r;
    if (row < total1) { src = h1; dst = h1b; sq = sq1; r = row; }
    else              { src = h2; dst = h2b; sq = sq2; r = row - total1; }

    const float4* p = (const float4*)(src + (size_t)r * DD) + l5 * 2;
    float4 a = p[0], c = p[1];

    float s = a.x*a.x + a.y*a.y + a.z*a.z + a.w*a.w
            + c.x*c.x + c.y*c.y + c.z*c.z + c.w*c.w;
    #pragma unroll
    for (int off = 16; off; off >>= 1) s += __shfl_xor(s, off, 64);

    short8 o;
    o[0] = f2bf(a.x); o[1] = f2bf(a.y); o[2] = f2bf(a.z); o[3] = f2bf(a.w);
    o[4] = f2bf(c.x); o[5] = f2bf(c.y); o[6] = f2bf(c.z); o[7] = f2bf(c.w);
    *(short8*)((char*)(dst + (size_t)r * DD) + l5 * 16) = o;

    if (l5 == 0) sq[r] = s;
}

// ---------------------------------------------------------------------------
// A-resident batched GEMM + fused Hausdorff epilogue, clean counted-vmcnt.
// Grid (32 b, 8 n-tiles) = 256 blocks, 1/CU. 512 thr = 8 waves (2n x 4m;
// wave tile 64n x 32m). A panel 128x256 -> registers (af[4][8], 128 VGPR);
// LDS A-region is then REUSED as B-buffers 2/3 (4-deep ring) so the
// compiler cannot rematerialize af reads. B streamed as 16 KB chunks,
// ONE barrier per step, exact vmcnt counting (zero other in-loop vmem:
// colmin via LDS atomics, rowmin in regs, sq2/s1 prefetched).
// ---------------------------------------------------------------------------
__global__ __launch_bounds__(512, 2) void gemm_kernel(
        const unsigned short* __restrict__ h1b, const unsigned short* __restrict__ h2b,
        const float* __restrict__ sq1, const float* __restrict__ sq2,
        unsigned int* __restrict__ rowmin, unsigned int* __restrict__ colmin) {
    __shared__ __align__(16) char pool[106496];  // 104 KB
    // [0,64K): A panel (prologue) THEN B-bufs 2,3   [64K,96K): B-bufs 0,1
    // [96K,100K): sq2_lds   [100K,104K): colmin_lds
    #define BUF0 (pool + 65536)
    #define BUF1 (pool + 81920)
    #define BUF2 (pool + 0)
    #define BUF3 (pool + 16384)
    float*        sq2_lds = (float*)(pool + 98304);
    unsigned int* cl      = (unsigned int*)(pool + 102400);

    const int b    = blockIdx.x;       // batch; XCD = b%8
    const int tile = blockIdx.y;       // n-tile 0..7
    const int n0   = tile * 128;

    const int tid  = threadIdx.x;
    const int wave = tid >> 6;         // 0..7
    const int lane = tid & 63;
    const int wn   = (wave >> 2) * 64;     // {0,64}
    const int wm   = (wave & 3) * 32;      // {0,32,64,96}

    const char* Ag = (const char*)(h1b + ((size_t)b * NN + n0) * DD);
    const char* Bg = (const char*)(h2b + (size_t)b * MM * DD);

    const int krow = lane >> 4;   // 0..3
    const int rrow = lane & 15;   // 0..15
    const int rx   = rrow & 7;
    const int lrow = krow * 4;
    const int lcol = rrow;

    // colmin LDS init (plain stores; consumed after barriers)
    cl[tid] = 0x7F800000u; cl[tid + 512] = 0x7F800000u;

    // ---- prologue vmem (in issue order; counted) ----
    // 1) s1 norms: 4 x float4 (registers)
    const float4* s1p = (const float4*)(sq1 + b * NN + n0 + wn + lrow);
    float4 s1v4[4];
    #pragma unroll
    for (int i = 0; i < 4; ++i) s1v4[i] = s1p[i * 4];

    // 2) sq2 -> LDS (2 copies)
    #pragma unroll
    for (int t = 0; t < 2; ++t)
        async_copy4(pool + 98304 + t * 2048 + wave * 256,
                    (const char*)(sq2 + b * MM) + t * 2048 + wave * 256 + lane * 4);

    // 3) A panel 64 KB (8 copies), inverse-swizzled source
    #pragma unroll
    for (int t = 0; t < 8; ++t) {
        int ch = t * 8 + wave;
        int r  = ch * 2 + (lane >> 5);
        int cu = (lane & 31) ^ (r & 7);
        async_copy16(pool + ch * 1024, Ag + (size_t)r * 512 + (cu << 4));
    }

    // 4) B stage macro: 16 KB chunk (m-tile mt, k-step ks) -> BUFP
    const int rl  = lane >> 3;
    const int bcu = (lane & 7) ^ rl;
    #define STAGE(mt_, ks_, BUFP)                                             \
        {                                                                     \
            _Pragma("unroll")                                                 \
            for (int c = 0; c < 2; ++c) {                                     \
                int ch_ = wave * 2 + c;                                       \
                int r_  = ch_ * 8 + rl;                                       \
                async_copy16((char*)(BUFP) + ch_ * 1024,                      \
                             Bg + (size_t)((mt_) * 128 + r_) * 512            \
                                + (size_t)(ks_) * 128 + (bcu << 4));          \
            }                                                                 \
        }

    STAGE(0, 0, BUF0);
    STAGE(0, 1, BUF1);

    // s1 + sq2 + A done; stage0/1 (4 copies) may stay in flight
    asm volatile("s_waitcnt vmcnt(4)" ::: "memory");
    __builtin_amdgcn_s_barrier();
    __builtin_amdgcn_sched_barrier(0);

    // ---- A panel -> registers ----
    short8 af[4][8];
    #pragma unroll
    for (int i = 0; i < 4; ++i) {
        #pragma unroll
        for (int kq = 0; kq < 8; ++kq) {
            int u = (kq * 4 + krow) ^ rx;
            af[i][kq] = *(const short8*)(pool
                        + (size_t)(wn + i * 16 + rrow) * 512 + (u << 4));
        }
    }
    asm volatile("s_waitcnt lgkmcnt(0)" ::: "memory");
    __builtin_amdgcn_s_barrier();
    __builtin_amdgcn_sched_barrier(0);
    // A region now dead -> usable as BUF2/BUF3
    STAGE(0, 2, BUF2);

    float rmin[4][4];
    #pragma unroll
    for (int i = 0; i < 4; ++i)
        #pragma unroll
        for (int r = 0; r < 4; ++r) rmin[i][r] = 3.0e38f;

    // ---- main loop: 8 m-tiles x 4 k-steps; buffers ring = step % 4 ----
    #pragma unroll 1
    for (int mt = 0; mt < 8; ++mt) {
        floatx4 acc[4][2] = {};

        #pragma unroll
        for (int ks = 0; ks < 4; ++ks) {
            // wait: stage(s) done; stages s+1,s+2 (4 copies) in flight
            if (mt == 7 && ks == 2)      { asm volatile("s_waitcnt vmcnt(2)" ::: "memory"); }
            else if (mt == 7 && ks == 3) { asm volatile("s_waitcnt vmcnt(0)" ::: "memory"); }
            else                         { asm volatile("s_waitcnt vmcnt(4)" ::: "memory"); }
            __builtin_amdgcn_s_barrier();
            __builtin_amdgcn_sched_barrier(0);

            // stage step s+3 into ring buffer (s+3)%4
            if (ks == 0)          { STAGE(mt,     3, BUF3); }
            else if (mt < 7) {
                if (ks == 1)      { STAGE(mt + 1, 0, BUF0); }
                else if (ks == 2) { STAGE(mt + 1, 1, BUF1); }
                else              { STAGE(mt + 1, 2, BUF2); }
            }

            // compute step s from ring buffer ks
            const char* Bb = (ks == 0) ? BUF0 : (ks == 1) ? BUF1
                           : (ks == 2) ? BUF2 : BUF3;
            __builtin_amdgcn_s_setprio(1);
            #pragma unroll
            for (int kk = 0; kk < 2; ++kk) {
                const int u = ((kk << 2) | krow) ^ rx;
                short8 bfv[2];
                #pragma unroll
                for (int j = 0; j < 2; ++j)
                    bfv[j] = *(const short8*)(Bb
                             + (size_t)(wm + j * 16 + rrow) * 128 + (u << 4));
                #pragma unroll
                for (int i = 0; i < 4; ++i)
                    #pragma unroll
                    for (int j = 0; j < 2; ++j)
                        acc[i][j] = __builtin_amdgcn_mfma_f32_16x16x32_bf16(
                            af[i][ks * 2 + kk], bfv[j], acc[i][j], 0, 0, 0);
            }
            __builtin_amdgcn_s_setprio(0);
        }

        // ---- per-mt epilogue: regs + LDS only (no vmem!) ----
        float s2v0 = sq2_lds[mt * 128 + wm + lcol];
        float s2v1 = sq2_lds[mt * 128 + wm + 16 + lcol];

        float cmin0 = 3.0e38f, cmin1 = 3.0e38f;
        #pragma unroll
        for (int i = 0; i < 4; ++i) {
            #pragma unroll
            for (int r = 0; r < 4; ++r) {
                float s1x = ((const float*)&s1v4[i])[r];
                float d0 = fmaxf(s1x + s2v0 - 2.0f * acc[i][0][r], 0.0f);
                float d1 = fmaxf(s1x + s2v1 - 2.0f * acc[i][1][r], 0.0f);
                rmin[i][r] = fminf(rmin[i][r], fminf(d0, d1));
                cmin0 = fminf(cmin0, d0);
                cmin1 = fminf(cmin1, d1);
            }
        }
        cmin0 = fminf(cmin0, __shfl_xor(cmin0, 16, 64));
        cmin0 = fminf(cmin0, __shfl_xor(cmin0, 32, 64));
        cmin1 = fminf(cmin1, __shfl_xor(cmin1, 16, 64));
        cmin1 = fminf(cmin1, __shfl_xor(cmin1, 32, 64));
        if (lane < 16) {
            atomicMin(&cl[mt * 128 + wm + lcol],      __float_as_uint(cmin0));
            atomicMin(&cl[mt * 128 + wm + 16 + lcol], __float_as_uint(cmin1));
        }
    }

    // ---- final rowmin (global atomics, out of loop) ----
    unsigned int* rm = rowmin + b * NN + n0;
    #pragma unroll
    for (int i = 0; i < 4; ++i) {
        #pragma unroll
        for (int r = 0; r < 4; ++r) {
            float v = rmin[i][r];
            #pragma unroll
            for (int off = 1; off < 16; off <<= 1)
                v = fminf(v, __shfl_xor(v, off, 64));
            if (lcol == 0)
                atomicMin(&rm[wn + i * 16 + lrow + r], __float_as_uint(v));
        }
    }

    // ---- colmin flush: LDS -> global (once) ----
    __syncthreads();
    unsigned int* cmg = colmin + b * MM;
    atomicMin(&cmg[tid],       cl[tid]);
    atomicMin(&cmg[tid + 512], cl[tid + 512]);
    #undef STAGE
    #undef BUF0
    #undef BUF1
    #undef BUF2
    #undef BUF3
}

// ---------------------------------------------------------------------------
__global__ __launch_bounds__(256) void finalize_kernel(
        const unsigned int* __restrict__ rowmin,
        const unsigned int* __restrict__ colmin,
        float* __restrict__ out) {
    int b = blockIdx.x;
    int tid = threadIdx.x;
    float s = 0.0f;
    for (int i = tid; i < NN; i += 256) s += __uint_as_float(rowmin[b * NN + i]);
    for (int i = tid; i < MM; i += 256) s += __uint_as_float(colmin[b * MM + i]);
    #pragma unroll
    for (int off = 32; off; off >>= 1) s += __shfl_xor(s, off, 64);
    __shared__ float wsum[4];
    if ((tid & 63) == 0) wsum[tid >> 6] = s;
    __syncthreads();
    if (tid == 0) out[b] = (wsum[0] + wsum[1] + wsum[2] + wsum[3]) * (1.0f / 1024.0f);
}

// ---------------------------------------------------------------------------
extern "C" void kernel_launch(void* const* d_in, const int* in_sizes, int n_in,
                              void* d_out, int out_size, void* d_ws, size_t ws_size,
                              hipStream_t stream) {
    const float* h1 = (const float*)d_in[0];
    const float* h2 = (const float*)d_in[1];
    float* out = (float*)d_out;

    char* ws = (char*)d_ws;
    const size_t bf_bytes = (size_t)BB * NN * DD * sizeof(unsigned short); // 16 MB
    unsigned short* h1b = (unsigned short*)ws;
    unsigned short* h2b = (unsigned short*)(ws + bf_bytes);
    float* sq1 = (float*)(ws + 2 * bf_bytes);
    float* sq2 = sq1 + BB * NN;
    unsigned int* rowmin = (unsigned int*)(sq2 + BB * MM);
    unsigned int* colmin = rowmin + BB * NN;

    // convert + norms + min-buffer init (rowmin/colmin contiguous)
    hipLaunchKernelGGL(convert_kernel, dim3(8192), dim3(256), 0, stream,
                       h1, h2, h1b, h2b, sq1, sq2, rowmin);

    hipLaunchKernelGGL(gemm_kernel, dim3(BB, 8), dim3(512), 0, stream,
                       h1b, h2b, sq1, sq2, rowmin, colmin);

    hipLaunchKernelGGL(finalize_kernel, dim3(BB), dim3(256), 0, stream,
                       rowmin, colmin, out);
}